// Round 6
// baseline (535.907 us; speedup 1.0000x reference)
//
#include <hip/hip_runtime.h>

typedef _Float16 f16x8 __attribute__((ext_vector_type(8)));
typedef _Float16 f16x4 __attribute__((ext_vector_type(4)));
typedef float    f32x4 __attribute__((ext_vector_type(4)));

#define MFMA(a,b,c) __builtin_amdgcn_mfma_f32_16x16x32_f16((a),(b),(c),0,0,0)

// ws layout (bytes): [0)      M~  f16 [128][128]  (scale * Wk^T Wq)
//                    [32768)  Wv' f16 [128][128]  (Wo @ Wv)
//                    [65536)  biases f32: t[128] = scale*Wk^T bq, b'[128] = Wo bv + bo
//                    [131072) Xg f16 [1024 g][256 rows=(d*8+p)][128 c]  (67.1 MB)
// Algebra: softmax over key-axis i is invariant to per-j offsets, so
//   S[i][j] = x_i^T (M x_j + t)  with M = scale*Wk^T Wq, t = scale*Wk^T bq
// (bk-only and constant terms drop). out = Wv' (X A) + b' + x.

// ---------------- prep: fold weights ----------------
__global__ __launch_bounds__(128) void prep_kernel(
    const float* __restrict__ Wk, const float* __restrict__ bk,
    const float* __restrict__ Wq, const float* __restrict__ bq,
    const float* __restrict__ Wv, const float* __restrict__ bv,
    const float* __restrict__ Wo, const float* __restrict__ bo,
    _Float16* __restrict__ wh, float* __restrict__ bf) {
  __shared__ float shK[128], shO[128];
  const int o = blockIdx.x;
  const int c = threadIdx.x;
  const float scale = 0.08838834764831844f;  // 1/sqrt(128)
  shK[c] = Wk[c*128 + o];      // Wk[m][o]  (column o)
  shO[c] = Wo[o*128 + c];      // Wo[o][m]
  __syncthreads();
  float aM = 0.f, aV = 0.f, tK = 0.f, bV = 0.f;
  for (int m = 0; m < 128; ++m) {
    aM += shK[m] * Wq[m*128 + c];   // M[o][c]
    aV += shO[m] * Wv[m*128 + c];   // Wv'[o][c]
    tK += shK[m] * bq[m];
    bV += shO[m] * bv[m];
  }
  wh[o*128 + c]         = (_Float16)(aM * scale);
  wh[16384 + o*128 + c] = (_Float16)aV;
  if (c == 0) { bf[o] = tK * scale; bf[128 + o] = bV + bo[o]; }
}

// ---------------- transpose v2: x fp32 [b,c,d,h,w] -> Xg f16 [g][d*8+p][c] ----------------
// grid = B*D*H = 4096 blocks, 256 thr. Lane packs 4 c's -> ds_write_b64.
__global__ __launch_bounds__(256) void transpose_kernel(
    const float* __restrict__ x, _Float16* __restrict__ Xg) {
  __shared__ _Float16 Lt[64 * 132];          // [w][c], stride 132 (264B, 8B-aligned rows)
  const int bid = blockIdx.x;
  const int h = bid & 63, d = (bid >> 6) & 31, b = bid >> 11;
  const int tid = threadIdx.x;
  const int wq = tid & 15, cr = tid >> 4;    // cr in [0,16)
  const size_t rbase = (size_t)b*16777216u + (size_t)d*4096 + h*64;
#pragma unroll
  for (int pass = 0; pass < 2; ++pass) {
    const int base_c = pass*64 + cr*4;
    f32x4 v[4];
#pragma unroll
    for (int r = 0; r < 4; ++r)
      v[r] = *(const f32x4*)(x + rbase + (size_t)(base_c + r)*131072 + wq*4);
#pragma unroll
    for (int p = 0; p < 4; ++p) {
      f16x4 t;
#pragma unroll
      for (int r = 0; r < 4; ++r) t[r] = (_Float16)v[r][p];
      *(f16x4*)(Lt + (wq*4 + p)*132 + base_c) = t;
    }
  }
  __syncthreads();
  // write: per w-row, 128 c contiguous (256B segments, line-aligned)
  const int gbase = (b*64 + h)*8;            // 8 groups per (b,h)
#pragma unroll
  for (int i = 0; i < 4; ++i) {
    const int idx = tid + i*256;             // 0..1023
    const int w = idx >> 4, ck = (idx & 15) * 8;
    const f16x8 v = *(const f16x8*)(Lt + w*132 + ck);
    *(f16x8*)(Xg + (size_t)(gbase + (w>>3))*32768 + (d*8 + (w&7))*128 + ck) = v;
  }
}

__device__ __forceinline__ f16x4 cvt4(f32x4 v, f32x4 b) {
  f16x4 r;
  r[0] = (_Float16)(v[0] + b[0]); r[1] = (_Float16)(v[1] + b[1]);
  r[2] = (_Float16)(v[2] + b[2]); r[3] = (_Float16)(v[3] + b[3]);
  return r;
}
__device__ __forceinline__ f16x4 cvt4z(f32x4 v) {
  f16x4 r;
  r[0] = (_Float16)v[0]; r[1] = (_Float16)v[1];
  r[2] = (_Float16)v[2]; r[3] = (_Float16)v[3];
  return r;
}

// XOR swizzle for Xt/Yt [256 rows][128 f16 cols], 256B rows, no padding.
// XOR folds row, row>>3 (stride-8-row accesses) and row>>5 (stride-64) so
// all phase patterns land >=8 distinct 16B chunks per 16 lanes.
__device__ __forceinline__ int xsw(int row, int col /*f16 units*/) {
  return ((row << 8) | (col << 1)) ^ (((row ^ (row >> 3) ^ (row >> 5)) & 7) << 4);
}

// ---------------- fused attention (persistent: 256 blocks x 4 iters, N=8) ----------------
// 8 consecutive w per group -> every store is a lone 32B granule = native HBM
// sector: WRITE amplification is timing-independent (round-5: 143MB ~= ideal),
// so persistence is now safe (round-3's failure was 16B-granule sibling desync).
// Persistence overlaps iter-k P6 store drain with iter-k+1 P1/P2 compute and
// kills 3 of 4 per-CU block ramp cycles. Next group's Xg prefetched to regs
// after P5 (contiguous, mostly L3 hits). LDS 148KB -> 1 block/CU.
__global__ __launch_bounds__(1024, 4) void attn_kernel(
    const _Float16* __restrict__ Xg, const _Float16* __restrict__ wh,
    const float* __restrict__ bfp, float* __restrict__ out) {
  __shared__ __align__(16) char lds[151552];
  char* XtB = lds;                      // [256 r=d*8+p][128 c] f16, swizzled (64KB)
  char* YtB = lds + 65536;              // Y^T, later U^T, swizzled (64KB)
  _Float16* At = (_Float16*)(lds + 131072);  // [p*32+j][40 i] f16 (20KB)

  const int tid  = threadIdx.x;
  const int lane = tid & 63;
  const int wv   = tid >> 6;            // 0..15
  const int quad = lane >> 4;
  const int l15  = lane & 15;
  const int bid  = blockIdx.x;          // 0..255
  const f32x4 zz = {0.f, 0.f, 0.f, 0.f};

  // P1 slot addresses (idx*8 f16 = contiguous global; row/ck for LDS swizzle)
  const int rowi[4] = { (tid)>>4, (tid+1024)>>4, (tid+2048)>>4, (tid+3072)>>4 };
  const int cki [4] = { (tid&15)*8, (tid&15)*8, (tid&15)*8, (tid&15)*8 };

  // ---- resident weight fragments + biases ----
  const int mi = wv & 7, ni = wv >> 3;
  f16x8 wm[4];
#pragma unroll
  for (int kk = 0; kk < 4; ++kk)
    wm[kk] = *(const f16x8*)(wh + (mi*16 + l15)*128 + kk*32 + quad*8);
  const f32x4 t4 = *(const f32x4*)(bfp + mi*16 + quad*4);
  const float bb = bfp[128 + (wv & 7)*16 + l15];   // P6 bias (oi = wv&7)

  // sibling pairing swizzle: g and g^1 are bids 8 apart -> same XCD
  int orig = bid;
  int g = (orig & ~15) | ((orig & 7) << 1) | ((orig >> 3) & 1);

  // ---- prefetch iter-0 Xg tile (4 x f16x8 = 64KB/block, contiguous) ----
  f16x8 pf[4];
#pragma unroll
  for (int i = 0; i < 4; ++i)
    pf[i] = *(const f16x8*)(Xg + (size_t)g*32768 + (size_t)(tid + i*1024)*8);

  for (int it = 0; it < 4; ++it) {
    const int b   = g >> 9;
    const int rem = g & 511;
    const size_t pbase = (size_t)b * 16777216u
                       + (size_t)((rem >> 3)*64 + (rem & 7)*8);

    // ---- P1: prefetched registers -> Xt (swizzled) ----
#pragma unroll
    for (int i = 0; i < 4; ++i)
      *(f16x8*)(XtB + xsw(rowi[i], cki[i])) = pf[i];
    __syncthreads();

    // ---- P2: Y = M~ X + t  -> Yt (rows = voxel d*8+p, cols = c1) ----
    {
      f32x4 aY[8] = {zz, zz, zz, zz, zz, zz, zz, zz};
#pragma unroll
      for (int kk = 0; kk < 4; ++kk) {
        const int co = kk*32 + quad*8;
#pragma unroll
        for (int nt = 0; nt < 8; ++nt) {
          const f16x8 bfv = *(const f16x8*)(XtB + xsw(ni*128 + nt*16 + l15, co));
          aY[nt] = MFMA(wm[kk], bfv, aY[nt]);
        }
      }
#pragma unroll
      for (int nt = 0; nt < 8; ++nt)
        *(f16x4*)(YtB + xsw(ni*128 + nt*16 + l15, mi*16 + quad*4)) = cvt4(aY[nt], t4);
    }
    __syncthreads();

    // ---- P3: S = X^T Y per pixel; wave = (pixel p, j-half tj); softmax -> At ----
    {
      const int p = wv & 7, tj = wv >> 3;
      f32x4 aS[2] = {zz, zz};
#pragma unroll
      for (int kk = 0; kk < 4; ++kk) {
        const int co = kk*32 + quad*8;
        const f16x8 by = *(const f16x8*)(YtB + xsw((tj*16 + l15)*8 + p, co));
#pragma unroll
        for (int ti = 0; ti < 2; ++ti) {
          const f16x8 ak = *(const f16x8*)(XtB + xsw((ti*16 + l15)*8 + p, co));
          aS[ti] = MFMA(ak, by, aS[ti]);
        }
      }
      // lane holds S[i = ti*16+quad*4+r][j = tj*16+l15]; reduce over i
      float mx = aS[0][0];
#pragma unroll
      for (int r = 1; r < 4; ++r) mx = fmaxf(mx, aS[0][r]);
#pragma unroll
      for (int r = 0; r < 4; ++r) mx = fmaxf(mx, aS[1][r]);
      mx = fmaxf(mx, __shfl_xor(mx, 16));
      mx = fmaxf(mx, __shfl_xor(mx, 32));
      float e[2][4];
      float den = 0.f;
#pragma unroll
      for (int ti = 0; ti < 2; ++ti)
#pragma unroll
        for (int r = 0; r < 4; ++r) { e[ti][r] = __expf(aS[ti][r] - mx); den += e[ti][r]; }
      den += __shfl_xor(den, 16);
      den += __shfl_xor(den, 32);
      const float rr = 1.0f / den;
#pragma unroll
      for (int ti = 0; ti < 2; ++ti) {
        f16x4 av;
#pragma unroll
        for (int r = 0; r < 4; ++r) av[r] = (_Float16)(e[ti][r] * rr);
        *(f16x4*)(At + (p*32 + tj*16 + l15)*40 + ti*16 + quad*4) = av;
      }
    }
    __syncthreads();

    // ---- P5: U = X A per pixel -> Yt (U^T rows = j*8+p); load Wv' frags ----
    f16x8 wp[4];
    {
#pragma unroll
      for (int kk = 0; kk < 4; ++kk)
        wp[kk] = *(const f16x8*)(wh + 16384 + (mi*16 + l15)*128 + kk*32 + quad*8);
      const int p = wv & 7, mg = wv >> 3;
      f16x8 bA[2];
#pragma unroll
      for (int tj = 0; tj < 2; ++tj)
        bA[tj] = *(const f16x8*)(At + (p*32 + tj*16 + l15)*40 + quad*8);
#pragma unroll
      for (int t2 = 0; t2 < 4; ++t2) {
        const int ms = mg*4 + t2;
        f16x8 ax;
#pragma unroll
        for (int jj = 0; jj < 8; ++jj)
          ax[jj] = *(const _Float16*)(XtB + xsw((quad*8 + jj)*8 + p, ms*16 + l15));
#pragma unroll
        for (int tj = 0; tj < 2; ++tj) {
          const f32x4 aU = MFMA(ax, bA[tj], zz);
          *(f16x4*)(YtB + xsw((tj*16 + l15)*8 + p, ms*16 + quad*4)) = cvt4z(aU);
        }
      }
    }

    // ---- prefetch next group's Xg (hides L3/HBM latency under P6) ----
    if (it < 3) {
      orig += 256;
      g = (orig & ~15) | ((orig & 7) << 1) | ((orig >> 3) & 1);
#pragma unroll
      for (int i = 0; i < 4; ++i)
        pf[i] = *(const f16x8*)(Xg + (size_t)g*32768 + (size_t)(tid + i*1024)*8);
    }
    __syncthreads();   // P5's Yt writes visible before P6 reads

    // ---- P6: out^T = U^T Wv'^T + b' + x : 32B/line stores (quad pairs) ----
    {
      const int oi = wv & 7, mg6 = wv >> 3;
      f32x4 acc[8] = {zz, zz, zz, zz, zz, zz, zz, zz};
#pragma unroll
      for (int kk = 0; kk < 4; ++kk) {
        const int co = kk*32 + quad*8;
#pragma unroll
        for (int mt = 0; mt < 8; ++mt) {
          const f16x8 av = *(const f16x8*)(YtB + xsw((mg6*8 + mt)*16 + l15, co));
          acc[mt] = MFMA(av, wp[kk], acc[mt]);
        }
      }
      const int o = oi*16 + l15;
      float* outp = out + pbase + (size_t)o*131072;
#pragma unroll
      for (int mt = 0; mt < 8; ++mt) {
        const int vox0 = (mg6*8 + mt)*16 + quad*4;   // voxel = d*8 + p
        const int d = vox0 >> 3;
        f32x4 v;
#pragma unroll
        for (int r = 0; r < 4; ++r)
          v[r] = acc[mt][r] + bb +
                 (float)*(const _Float16*)(XtB + xsw(vox0 + r, o));
        *(f32x4*)(outp + (size_t)d*4096 + (vox0 & 7)) = v;
      }
    }
    __syncthreads();   // all P6 LDS reads done before next iter's Xt/Yt writes
  }
}

extern "C" void kernel_launch(void* const* d_in, const int* in_sizes, int n_in,
                              void* d_out, int out_size, void* d_ws, size_t ws_size,
                              hipStream_t stream) {
  const float* x  = (const float*)d_in[0];
  const float* Wk = (const float*)d_in[1];
  const float* bk = (const float*)d_in[2];
  const float* Wq = (const float*)d_in[3];
  const float* bq = (const float*)d_in[4];
  const float* Wv = (const float*)d_in[5];
  const float* bv = (const float*)d_in[6];
  const float* Wo = (const float*)d_in[7];
  const float* bo = (const float*)d_in[8];
  float* out = (float*)d_out;
  _Float16* wh = (_Float16*)d_ws;
  float* bf = (float*)((char*)d_ws + 65536);
  _Float16* Xg = (_Float16*)((char*)d_ws + 131072);  // needs 67.1 MB of ws

  prep_kernel<<<dim3(128), dim3(128), 0, stream>>>(Wk, bk, Wq, bq, Wv, bv, Wo, bo, wh, bf);
  transpose_kernel<<<dim3(4096), dim3(256), 0, stream>>>(x, Xg);
  attn_kernel<<<dim3(256), dim3(1024), 0, stream>>>(Xg, wh, bf, out);
}

// Round 7
// 347.362 us; speedup vs baseline: 1.5428x; 1.5428x over previous
//
#include <hip/hip_runtime.h>

typedef _Float16 f16x8 __attribute__((ext_vector_type(8)));
typedef _Float16 f16x4 __attribute__((ext_vector_type(4)));
typedef float    f32x4 __attribute__((ext_vector_type(4)));

#define MFMA(a,b,c) __builtin_amdgcn_mfma_f32_16x16x32_f16((a),(b),(c),0,0,0)

// ws layout (bytes): [0)      M~  f16 [128][128]  (scale * Wk^T Wq)
//                    [32768)  Wv' f16 [128][128]  (Wo @ Wv)
//                    [65536)  biases f32: t[128] = scale*Wk^T bq, b'[128] = Wo bv + bo
// Algebra: softmax over key-axis i is invariant to per-j offsets, so
//   S[i][j] = x_i^T (M x_j + t)  with M = scale*Wk^T Wq, t = scale*Wk^T bq
// (bk-only and constant terms drop). out = Wv' (X A) + b' + x.
//
// Design rules established R0-R6 (hard-won):
//  - NON-persistent, phase-aligned dispatch only (persistence desyncs sibling
//    stores -> L2/L3 partial-line RMW: R3 +290MB FETCH, R6 +250MB).
//  - Store granule must be >=32B (N=8 w per block); siblings (bid,bid+8) are
//    co-round + same-XCD so L2 completes each 64B line (R5: WRITE 143MB~ideal).
//  - x is read fused (32B granules per (c,d)); sibling blocks share each 64B
//    x-line in L2 (read merge has no eviction race, unlike writes).

// ---------------- prep: fold weights ----------------
__global__ __launch_bounds__(128) void prep_kernel(
    const float* __restrict__ Wk, const float* __restrict__ bk,
    const float* __restrict__ Wq, const float* __restrict__ bq,
    const float* __restrict__ Wv, const float* __restrict__ bv,
    const float* __restrict__ Wo, const float* __restrict__ bo,
    _Float16* __restrict__ wh, float* __restrict__ bf) {
  __shared__ float shK[128], shO[128];
  const int o = blockIdx.x;
  const int c = threadIdx.x;
  const float scale = 0.08838834764831844f;  // 1/sqrt(128)
  shK[c] = Wk[c*128 + o];      // Wk[m][o]  (column o)
  shO[c] = Wo[o*128 + c];      // Wo[o][m]
  __syncthreads();
  float aM = 0.f, aV = 0.f, tK = 0.f, bV = 0.f;
  for (int m = 0; m < 128; ++m) {
    aM += shK[m] * Wq[m*128 + c];   // M[o][c]
    aV += shO[m] * Wv[m*128 + c];   // Wv'[o][c]
    tK += shK[m] * bq[m];
    bV += shO[m] * bv[m];
  }
  wh[o*128 + c]         = (_Float16)(aM * scale);
  wh[16384 + o*128 + c] = (_Float16)aV;
  if (c == 0) { bf[o] = tK * scale; bf[128 + o] = bV + bo[o]; }
}

__device__ __forceinline__ f16x4 cvt4(f32x4 v, f32x4 b) {
  f16x4 r;
  r[0] = (_Float16)(v[0] + b[0]); r[1] = (_Float16)(v[1] + b[1]);
  r[2] = (_Float16)(v[2] + b[2]); r[3] = (_Float16)(v[3] + b[3]);
  return r;
}
__device__ __forceinline__ f16x4 cvt4z(f32x4 v) {
  f16x4 r;
  r[0] = (_Float16)v[0]; r[1] = (_Float16)v[1];
  r[2] = (_Float16)v[2]; r[3] = (_Float16)v[3];
  return r;
}

// XOR swizzle for Xt/Yt [256 rows][128 f16 cols], 256B rows, no padding.
// XOR folds row, row>>3 (stride-8-row accesses) and row>>5 (stride-64) so
// all phase patterns land >=8 distinct 16B chunks per 16 lanes. The XOR only
// permutes 16B chunks (byte bits 4..6), so 8B-aligned sub-writes stay intact.
__device__ __forceinline__ int xsw(int row, int col /*f16 units*/) {
  return ((row << 8) | (col << 1)) ^ (((row ^ (row >> 3) ^ (row >> 5)) & 7) << 4);
}

// ---------------- fused attention (N=8, transpose fused into P1) ----------------
// grid = 1024 blocks x 1024 thr; 8 consecutive w per block. P1 reads x fp32
// directly (8 x f32x4 per thread = 4 c's x 8 w of one d), transposes in
// registers, ds_write_b64 (4 c's per write) into swizzled Xt. Eliminates the
// standalone transpose kernel and its 134MB Xg round-trip.
// LDS 148KB -> 1 block/CU: all CUs lockstep (the write-merge synchronizer).
__global__ __launch_bounds__(1024, 4) void attn_kernel(
    const float* __restrict__ x, const _Float16* __restrict__ wh,
    const float* __restrict__ bfp, float* __restrict__ out) {
  __shared__ __align__(16) char lds[151552];
  char* XtB = lds;                      // [256 r=d*8+p][128 c] f16, swizzled (64KB)
  char* YtB = lds + 65536;              // Y^T, later U^T, swizzled (64KB)
  _Float16* At = (_Float16*)(lds + 131072);  // [p*32+j][40 i] f16 (20KB)

  const int tid  = threadIdx.x;
  const int lane = tid & 63;
  const int wv   = tid >> 6;            // 0..15
  const int quad = lane >> 4;
  const int l15  = lane & 15;

  const int bid = blockIdx.x;
  // sibling pairing: g and g^1 (the two halves of each 64B out/x line) are
  // bids 8 apart -> same XCD (bid%8 equal), same dispatch round.
  const int g = (bid & ~15) | ((bid & 7) << 1) | ((bid >> 3) & 1);
  const int b   = g >> 9;
  const int rem = g & 511;
  const int h   = rem >> 3;
  const int wg  = rem & 7;
  const size_t pbase = (size_t)b * 16777216u + (size_t)(h*64 + wg*8);
  const f32x4 zz = {0.f, 0.f, 0.f, 0.f};

  // ---- P1 loads issued FIRST (longest latency) ----
  const int c4 = tid & 31;              // c-quad 0..31
  const int dd = tid >> 5;              // d 0..31
  f32x4 v[4][2];
  {
    const float* xg = x + pbase + (size_t)c4*4*131072 + (size_t)dd*4096;
#pragma unroll
    for (int r = 0; r < 4; ++r)
#pragma unroll
      for (int i = 0; i < 2; ++i)
        v[r][i] = *(const f32x4*)(xg + (size_t)r*131072 + i*4);
  }

  // ---- resident weight fragments + biases (overlap with x loads) ----
  const int mi = wv & 7, ni = wv >> 3;
  f16x8 wm[4];
#pragma unroll
  for (int kk = 0; kk < 4; ++kk)
    wm[kk] = *(const f16x8*)(wh + (mi*16 + l15)*128 + kk*32 + quad*8);
  const f32x4 t4 = *(const f32x4*)(bfp + mi*16 + quad*4);

  // ---- P1: register transpose -> Xt (swizzled), 8 x ds_write_b64 ----
#pragma unroll
  for (int i = 0; i < 2; ++i)
#pragma unroll
    for (int p = 0; p < 4; ++p) {
      f16x4 t;
#pragma unroll
      for (int r = 0; r < 4; ++r) t[r] = (_Float16)v[r][i][p];
      *(f16x4*)(XtB + xsw(dd*8 + i*4 + p, c4*4)) = t;
    }
  __syncthreads();

  // ---- P2: Y = M~ X + t  -> Yt (rows = voxel d*8+p, cols = c1) ----
  {
    f32x4 aY[8] = {zz, zz, zz, zz, zz, zz, zz, zz};
#pragma unroll
    for (int kk = 0; kk < 4; ++kk) {
      const int co = kk*32 + quad*8;
#pragma unroll
      for (int nt = 0; nt < 8; ++nt) {
        const f16x8 bfv = *(const f16x8*)(XtB + xsw(ni*128 + nt*16 + l15, co));
        aY[nt] = MFMA(wm[kk], bfv, aY[nt]);
      }
    }
#pragma unroll
    for (int nt = 0; nt < 8; ++nt)
      *(f16x4*)(YtB + xsw(ni*128 + nt*16 + l15, mi*16 + quad*4)) = cvt4(aY[nt], t4);
  }
  __syncthreads();

  // ---- P3: S = X^T Y per pixel; wave = (pixel p, j-half tj); softmax -> At ----
  {
    const int p = wv & 7, tj = wv >> 3;
    f32x4 aS[2] = {zz, zz};
#pragma unroll
    for (int kk = 0; kk < 4; ++kk) {
      const int co = kk*32 + quad*8;
      const f16x8 by = *(const f16x8*)(YtB + xsw((tj*16 + l15)*8 + p, co));
#pragma unroll
      for (int ti = 0; ti < 2; ++ti) {
        const f16x8 ak = *(const f16x8*)(XtB + xsw((ti*16 + l15)*8 + p, co));
        aS[ti] = MFMA(ak, by, aS[ti]);
      }
    }
    // lane holds S[i = ti*16+quad*4+r][j = tj*16+l15]; reduce over i
    float mx = aS[0][0];
#pragma unroll
    for (int r = 1; r < 4; ++r) mx = fmaxf(mx, aS[0][r]);
#pragma unroll
    for (int r = 0; r < 4; ++r) mx = fmaxf(mx, aS[1][r]);
    mx = fmaxf(mx, __shfl_xor(mx, 16));
    mx = fmaxf(mx, __shfl_xor(mx, 32));
    float e[2][4];
    float den = 0.f;
#pragma unroll
    for (int ti = 0; ti < 2; ++ti)
#pragma unroll
      for (int r = 0; r < 4; ++r) { e[ti][r] = __expf(aS[ti][r] - mx); den += e[ti][r]; }
    den += __shfl_xor(den, 16);
    den += __shfl_xor(den, 32);
    const float rr = 1.0f / den;
#pragma unroll
    for (int ti = 0; ti < 2; ++ti) {
      f16x4 av;
#pragma unroll
      for (int r = 0; r < 4; ++r) av[r] = (_Float16)(e[ti][r] * rr);
      *(f16x4*)(At + (p*32 + tj*16 + l15)*40 + ti*16 + quad*4) = av;
    }
  }
  __syncthreads();

  // ---- P5: U = X A per pixel -> Yt (U^T rows = j*8+p); prefetch Wv' ----
  f16x8 wp[4];
  {
#pragma unroll
    for (int kk = 0; kk < 4; ++kk)
      wp[kk] = *(const f16x8*)(wh + 16384 + (mi*16 + l15)*128 + kk*32 + quad*8);
    const int p = wv & 7, mg = wv >> 3;
    f16x8 bA[2];
#pragma unroll
    for (int tj = 0; tj < 2; ++tj)
      bA[tj] = *(const f16x8*)(At + (p*32 + tj*16 + l15)*40 + quad*8);
#pragma unroll
    for (int t2 = 0; t2 < 4; ++t2) {
      const int ms = mg*4 + t2;
      f16x8 ax;
#pragma unroll
      for (int jj = 0; jj < 8; ++jj)
        ax[jj] = *(const _Float16*)(XtB + xsw((quad*8 + jj)*8 + p, ms*16 + l15));
#pragma unroll
      for (int tj = 0; tj < 2; ++tj) {
        const f32x4 aU = MFMA(ax, bA[tj], zz);
        *(f16x4*)(YtB + xsw((tj*16 + l15)*8 + p, ms*16 + quad*4)) = cvt4z(aU);
      }
    }
  }
  __syncthreads();

  // ---- P6: out^T = U^T Wv'^T + b' + x : 32B/line stores (quad pairs) ----
  {
    const int oi = wv & 7, mg6 = wv >> 3;
    f32x4 acc[8] = {zz, zz, zz, zz, zz, zz, zz, zz};
#pragma unroll
    for (int kk = 0; kk < 4; ++kk) {
      const int co = kk*32 + quad*8;
#pragma unroll
      for (int mt = 0; mt < 8; ++mt) {
        const f16x8 av = *(const f16x8*)(YtB + xsw((mg6*8 + mt)*16 + l15, co));
        acc[mt] = MFMA(av, wp[kk], acc[mt]);
      }
    }
    const int o = oi*16 + l15;
    const float bb = bfp[128 + o];
    float* outp = out + pbase + (size_t)o*131072;
#pragma unroll
    for (int mt = 0; mt < 8; ++mt) {
      const int vox0 = (mg6*8 + mt)*16 + quad*4;   // voxel = d*8 + p
      const int d = vox0 >> 3;
      f32x4 vv;
#pragma unroll
      for (int r = 0; r < 4; ++r)
        vv[r] = acc[mt][r] + bb +
                (float)*(const _Float16*)(XtB + xsw(vox0 + r, o));
      *(f32x4*)(outp + (size_t)d*4096 + (vox0 & 7)) = vv;
    }
  }
}

extern "C" void kernel_launch(void* const* d_in, const int* in_sizes, int n_in,
                              void* d_out, int out_size, void* d_ws, size_t ws_size,
                              hipStream_t stream) {
  const float* x  = (const float*)d_in[0];
  const float* Wk = (const float*)d_in[1];
  const float* bk = (const float*)d_in[2];
  const float* Wq = (const float*)d_in[3];
  const float* bq = (const float*)d_in[4];
  const float* Wv = (const float*)d_in[5];
  const float* bv = (const float*)d_in[6];
  const float* Wo = (const float*)d_in[7];
  const float* bo = (const float*)d_in[8];
  float* out = (float*)d_out;
  _Float16* wh = (_Float16*)d_ws;
  float* bf = (float*)((char*)d_ws + 65536);

  prep_kernel<<<dim3(128), dim3(128), 0, stream>>>(Wk, bk, Wq, bq, Wv, bv, Wo, bo, wh, bf);
  attn_kernel<<<dim3(1024), dim3(1024), 0, stream>>>(x, wh, bf, out);
}